// Round 10
// baseline (98.280 us; speedup 1.0000x reference)
//
#include <hip/hip_runtime.h>
#include <hip/hip_bf16.h>

#define N_NODES 16000
#define IN_F 128
#define HID 64
#define BATCH 32
#define NPAIR 128
#define DRES 100
#define NCLS 10

// workspace layout (float offsets)
#define NF_OFF     0
#define WT1_OFF    16000                     // [2 ic][25 tap][16 oc] fp32
#define WT2B_OFF   (16000 + 800)             // [200 kp][32 oc] packed bf16 pairs (uint)
#define INV_OFF    (16000 + 800 + 12800)     // [64] per-(b,c) 1/max
#define IMGSP_OFF  (INV_OFF + 64)            // [32][2][104][104] padded
#define POOL1P_OFF (IMGSP_OFF + 32*2*104*104)   // [32][16][54][56] padded
#define POOL2_OFF  (POOL1P_OFF + 32*16*54*56)   // [32][32][25][25]
#define ZERO_N4    ((32*2*104*104 + 32*16*54*56) / 4)

#define NZBLK  ((ZERO_N4 + 255) / 256)

// float2 patch element access (compile-time index under full unroll)
#define PV(P, r, c) (((c) & 1) ? P[(r)*3 + ((c)>>1)].y : P[(r)*3 + ((c)>>1)].x)

typedef short short8 __attribute__((ext_vector_type(8)));
typedef float f32x16 __attribute__((ext_vector_type(16)));

static __device__ __forceinline__ unsigned short f2b(float f) {
    __hip_bfloat16 h = __float2bfloat16(f);
    return *reinterpret_cast<unsigned short*>(&h);
}

// element offset of k=(ic,kh,kw) within inb[16][6][56] (tile row-base 0)
#define COFF(k) (((k)/25)*336 + (((k)%25)/5)*56 + ((k)%25)%5)

// ---------------- Kernel I: weight prep + zero buffers ----------------
__global__ __launch_bounds__(256) void k_init(const float* __restrict__ c1w,
    const float* __restrict__ c2w, float* __restrict__ wT1, unsigned int* __restrict__ wT2b,
    float* __restrict__ zbase)
{
    int bx = blockIdx.x, t = threadIdx.x;
    if (bx == 0) {
        for (int i = t; i < 800; i += 256) {
            int ic = i / 400, tap = (i / 16) % 25, oc = i % 16;
            wT1[i] = c1w[(oc * 2 + ic) * 25 + tap];
        }
        return;
    }
    if (bx == 1) {
        // wT2b[kp][oc] = pack(bf16(W[2kp][oc]), bf16(W[2kp+1][oc])), k = ic*25+tap
        for (int i = t; i < 6400; i += 256) {
            int kp = i >> 5, oc = i & 31;
            int k0 = 2 * kp, k1 = k0 + 1;
            float f0 = c2w[(oc * 16 + k0 / 25) * 25 + k0 % 25];
            float f1 = c2w[(oc * 16 + k1 / 25) * 25 + k1 % 25];
            wT2b[i] = (unsigned int)f2b(f0) | ((unsigned int)f2b(f1) << 16);
        }
        return;
    }
    int i = (bx - 2) * 256 + t;
    if (i < ZERO_N4) ((float4*)zbase)[i] = make_float4(0.f, 0.f, 0.f, 0.f);
}

// ---------------- Kernel A: node filtration MLP, w1 staged in LDS ----------------
// 500 blocks x 256 thr; wave = 8 nodes, lane = hidden unit. w1 (32 KB) loaded
// once per block -> per-wave streaming of w1 from L2 (r9's 128 MB re-read) gone.
__global__ __launch_bounds__(256) void k_filt(const float* __restrict__ x,
    const float* __restrict__ w1, const float* __restrict__ b1,
    const float* __restrict__ w2, const float* __restrict__ b2,
    float* __restrict__ nf, float* __restrict__ out_nf)
{
    __shared__ float w1s[IN_F * HID];   // 32 KB
    int t = threadIdx.x;
    for (int i = t; i < IN_F * HID / 4; i += 256)
        ((float4*)w1s)[i] = ((const float4*)w1)[i];
    __syncthreads();

    int wave = t >> 6, lane = t & 63;
    int n0 = blockIdx.x * 32 + wave * 8;
    const float* x0 = x + (size_t)n0 * IN_F;

    float a[8] = {0.f, 0.f, 0.f, 0.f, 0.f, 0.f, 0.f, 0.f};
    #pragma unroll 4
    for (int k = 0; k < IN_F; ++k) {
        float wv = w1s[k * HID + lane];   // conflict-free (2 lanes/bank = free)
        a[0] = fmaf(x0[0 * IN_F + k], wv, a[0]);
        a[1] = fmaf(x0[1 * IN_F + k], wv, a[1]);
        a[2] = fmaf(x0[2 * IN_F + k], wv, a[2]);
        a[3] = fmaf(x0[3 * IN_F + k], wv, a[3]);
        a[4] = fmaf(x0[4 * IN_F + k], wv, a[4]);
        a[5] = fmaf(x0[5 * IN_F + k], wv, a[5]);
        a[6] = fmaf(x0[6 * IN_F + k], wv, a[6]);
        a[7] = fmaf(x0[7 * IN_F + k], wv, a[7]);
    }
    float bb = b1[lane], w2v = w2[lane];
    float p[8];
    #pragma unroll
    for (int j = 0; j < 8; ++j)
        p[j] = fmaxf(a[j] + bb, 0.f) * w2v;
    #pragma unroll
    for (int off = 32; off > 0; off >>= 1) {
        #pragma unroll
        for (int j = 0; j < 8; ++j)
            p[j] += __shfl_xor(p[j], off, 64);
    }
    if (lane < 8) {
        // static-index select (runtime p[lane] would go to scratch)
        float s = p[0];
        if (lane == 1) s = p[1];
        if (lane == 2) s = p[2];
        if (lane == 3) s = p[3];
        if (lane == 4) s = p[4];
        if (lane == 5) s = p[5];
        if (lane == 6) s = p[6];
        if (lane == 7) s = p[7];
        float f = 1.f / (1.f + expf(-(s + b2[0])));
        nf[n0 + lane] = f;
        out_nf[n0 + lane] = f;
    }
}

// ---------------- Kernel B: persistence image partial accumulate ----------------
__global__ __launch_bounds__(256) void k_pimg(const float* __restrict__ nf,
    const int* __restrict__ pi0, const int* __restrict__ pi1,
    float* __restrict__ imgs_p)
{
    int g = blockIdx.x;
    int img = (g & 7) * 8 + ((g >> 3) & 7);
    int q = g >> 6;
    int b = img >> 1, c = img & 1;
    const int* pi = c ? pi1 : pi0;
    __shared__ float sb[32], sp[32];
    int t = threadIdx.x;
    if (t < 32) {
        int p = q * 32 + t;
        int i0 = pi[(b * NPAIR + p) * 2 + 0];
        int i1 = pi[(b * NPAIR + p) * 2 + 1];
        float f0 = nf[i0], f1 = nf[i1];
        sb[t] = f0;
        sp[t] = f1 - f0;
    }
    __syncthreads();
    if (t >= 169) return;
    int ti = t / 13, tj = t % 13;
    float ci[8], cj[8];
    #pragma unroll
    for (int r = 0; r < 8; ++r) {
        ci[r] = (float)(ti + 13 * r) * 0.01f;
        cj[r] = (float)(tj + 13 * r) * 0.01f;
    }
    float acc[8][8];
    #pragma unroll
    for (int r = 0; r < 8; ++r)
        #pragma unroll
        for (int s = 0; s < 8; ++s) acc[r][s] = 0.f;
    for (int p = 0; p < 32; ++p) {
        float bb = sb[p], pp = sp[p];
        float eb[8], ep[8];
        #pragma unroll
        for (int r = 0; r < 8; ++r) { float d = bb - ci[r]; eb[r] = __expf(-d * d); }
        #pragma unroll
        for (int s = 0; s < 8; ++s) { float d = pp - cj[s]; ep[s] = __expf(-d * d); }
        #pragma unroll
        for (int r = 0; r < 8; ++r)
            #pragma unroll
            for (int s = 0; s < 8; ++s)
                acc[r][s] = fmaf(eb[r], ep[s], acc[r][s]);
    }
    float* dst = imgs_p + (size_t)img * 10816 + 2 * 104 + 2;
    #pragma unroll
    for (int r = 0; r < 8; ++r) {
        int i = ti + 13 * r;
        if (i < DRES) {
            #pragma unroll
            for (int s = 0; s < 8; ++s) {
                int j = tj + 13 * s;
                if (j < DRES) atomicAdd(&dst[i * 104 + j], acc[r][s]);
            }
        }
    }
}

// ---------------- Kernel M: per-image max -> inv ----------------
__global__ __launch_bounds__(256) void k_pmax(const float* __restrict__ imgs_p,
    float* __restrict__ inv)
{
    int img = blockIdx.x;
    const float4* src = (const float4*)(imgs_p + (size_t)img * 10816);
    int t = threadIdx.x;
    float m = 0.f;
    for (int k = t; k < 2704; k += 256) {
        float4 v = src[k];
        m = fmaxf(m, fmaxf(fmaxf(v.x, v.y), fmaxf(v.z, v.w)));
    }
    #pragma unroll
    for (int off = 32; off > 0; off >>= 1)
        m = fmaxf(m, __shfl_xor(m, off, 64));
    __shared__ float wm[4];
    if ((t & 63) == 0) wm[t >> 6] = m;
    __syncthreads();
    if (t == 0) {
        float bm = fmaxf(fmaxf(wm[0], wm[1]), fmaxf(wm[2], wm[3]));
        inv[img] = 1.f / bm;
    }
}

// ---------------- Kernel C: conv1 + relu + maxpool2 (VALU) ----------------
__global__ __launch_bounds__(256) void k_conv1(const float* __restrict__ imgs_p,
    const float* __restrict__ wT1, const float* __restrict__ cb,
    const float* __restrict__ inv, float* __restrict__ pool1p)
{
    int g = blockIdx.x;
    int b = (g & 7) * 4 + ((g >> 3) & 3);
    int ocg = (g >> 5) & 3;
    int rg = g >> 7;
    int t = threadIdx.x;
    if (t >= 250) return;
    int ow = t % 50, oh = rg * 5 + t / 50;

    float2 PA[18], PB[18];
    {
        const float* bs = imgs_p + (size_t)(b * 2 + 0) * 10816 + (2 * oh) * 104 + 2 * ow;
        #pragma unroll
        for (int r = 0; r < 6; ++r) {
            const float* rp = bs + r * 104;
            PA[r * 3 + 0] = *(const float2*)rp;
            PA[r * 3 + 1] = *(const float2*)(rp + 2);
            PA[r * 3 + 2] = *(const float2*)(rp + 4);
        }
        const float* bs1 = bs + 10816;
        #pragma unroll
        for (int r = 0; r < 6; ++r) {
            const float* rp = bs1 + r * 104;
            PB[r * 3 + 0] = *(const float2*)rp;
            PB[r * 3 + 1] = *(const float2*)(rp + 2);
            PB[r * 3 + 2] = *(const float2*)(rp + 4);
        }
    }
    float acc0[4][2][2] = {}, acc1[4][2][2] = {};
    const float* w0 = wT1 + ocg * 4;
    const float* w1r = wT1 + 400 + ocg * 4;
    #pragma unroll
    for (int kh = 0; kh < 5; ++kh)
        #pragma unroll
        for (int kw = 0; kw < 5; ++kw) {
            float4 wa = *(const float4*)(w0 + (kh * 5 + kw) * 16);
            float4 wb = *(const float4*)(w1r + (kh * 5 + kw) * 16);
            #pragma unroll
            for (int j = 0; j < 2; ++j)
                #pragma unroll
                for (int i = 0; i < 2; ++i) {
                    float va = PV(PA, kh + j, kw + i);
                    float vb = PV(PB, kh + j, kw + i);
                    acc0[0][j][i] = fmaf(va, wa.x, acc0[0][j][i]);
                    acc0[1][j][i] = fmaf(va, wa.y, acc0[1][j][i]);
                    acc0[2][j][i] = fmaf(va, wa.z, acc0[2][j][i]);
                    acc0[3][j][i] = fmaf(va, wa.w, acc0[3][j][i]);
                    acc1[0][j][i] = fmaf(vb, wb.x, acc1[0][j][i]);
                    acc1[1][j][i] = fmaf(vb, wb.y, acc1[1][j][i]);
                    acc1[2][j][i] = fmaf(vb, wb.z, acc1[2][j][i]);
                    acc1[3][j][i] = fmaf(vb, wb.w, acc1[3][j][i]);
                }
        }
    float sc0 = inv[b * 2 + 0], sc1 = inv[b * 2 + 1];
    float4 bias4 = *(const float4*)(cb + ocg * 4);
    float bv[4] = {bias4.x, bias4.y, bias4.z, bias4.w};
    #pragma unroll
    for (int o = 0; o < 4; ++o) {
        float v00 = fmaf(sc1, acc1[o][0][0], sc0 * acc0[o][0][0]);
        float v01 = fmaf(sc1, acc1[o][0][1], sc0 * acc0[o][0][1]);
        float v10 = fmaf(sc1, acc1[o][1][0], sc0 * acc0[o][1][0]);
        float v11 = fmaf(sc1, acc1[o][1][1], sc0 * acc0[o][1][1]);
        float m = fmaxf(fmaxf(v00, v01), fmaxf(v10, v11));
        pool1p[((size_t)(b * 16 + ocg * 4 + o) * 54 + oh + 2) * 56 + ow + 2] =
            fmaxf(m + bv[o], 0.f);
    }
}

// ---------------- Kernel D: conv2 via MFMA implicit GEMM ----------------
__global__ __launch_bounds__(128) void k_conv2(const float* __restrict__ pool1p,
    const unsigned int* __restrict__ wg, const float* __restrict__ cb2,
    float* __restrict__ pool2)
{
    int g = blockIdx.x;
    int b = (g & 7) * 4 + ((g >> 3) & 3);
    int py = g >> 5;
    int t = threadIdx.x;

    __shared__ unsigned short inb[5376];  // [16 ic][6 rows][56 cols] bf16
    {
        const float* src = pool1p + (size_t)b * 48384 + (2 * py) * 56;
        unsigned int* inb32 = (unsigned int*)inb;
        for (int i = t; i < 1344; i += 128) {
            int ic = i / 84, rem = i % 84;
            int r = rem / 14, c4 = rem % 14;
            float4 v = *(const float4*)(src + ic * 3024 + r * 56 + c4 * 4);
            inb32[i * 2 + 0] = (unsigned int)f2b(v.x) | ((unsigned int)f2b(v.y) << 16);
            inb32[i * 2 + 1] = (unsigned int)f2b(v.z) | ((unsigned int)f2b(v.w) << 16);
        }
    }
    __syncthreads();

    int lane = t & 63;
    int h = t >> 6;             // wave: spatial col-half
    int hh = lane >> 5;         // k-half within fragment
    int sm = lane & 31;         // A row (spatial) == B col (oc)
    int cb = h * 32 + sm; if (cb > 49) cb = 49;
    int cbA = cb, cbB = cb + 56;
    int oc = sm;
    int wbase = hh * 128 + oc;

    f32x16 accA = {0.f,0.f,0.f,0.f,0.f,0.f,0.f,0.f,0.f,0.f,0.f,0.f,0.f,0.f,0.f,0.f};
    f32x16 accB = {0.f,0.f,0.f,0.f,0.f,0.f,0.f,0.f,0.f,0.f,0.f,0.f,0.f,0.f,0.f,0.f};

    #pragma unroll
    for (int s = 0; s < 25; ++s) {
        union { short8 v; unsigned int u[4]; } bw;
        bw.u[0] = wg[wbase + s * 256 + 0];
        bw.u[1] = wg[wbase + s * 256 + 32];
        bw.u[2] = wg[wbase + s * 256 + 64];
        bw.u[3] = wg[wbase + s * 256 + 96];
        unsigned short ua[8], ub[8];
        #pragma unroll
        for (int e = 0; e < 8; ++e) {
            int o = hh ? COFF(16 * s + 8 + e) : COFF(16 * s + e);
            ua[e] = inb[cbA + o];
            ub[e] = inb[cbB + o];
        }
        union { short8 v; unsigned int u[4]; } aA, aB;
        #pragma unroll
        for (int r = 0; r < 4; ++r) {
            aA.u[r] = (unsigned int)ua[2 * r] | ((unsigned int)ua[2 * r + 1] << 16);
            aB.u[r] = (unsigned int)ub[2 * r] | ((unsigned int)ub[2 * r + 1] << 16);
        }
        accA = __builtin_amdgcn_mfma_f32_32x32x16_bf16(aA.v, bw.v, accA, 0, 0, 0);
        accB = __builtin_amdgcn_mfma_f32_32x32x16_bf16(aB.v, bw.v, accB, 0, 0, 0);
    }

    float bias = cb2[oc];
    float* dst = pool2 + ((size_t)(b * 32 + oc) * 25 + py) * 25;
    #pragma unroll
    for (int q = 0; q < 4; ++q) {
        float m0 = fmaxf(fmaxf(accA[4 * q + 0], accB[4 * q + 0]),
                         fmaxf(accA[4 * q + 1], accB[4 * q + 1]));
        float m1 = fmaxf(fmaxf(accA[4 * q + 2], accB[4 * q + 2]),
                         fmaxf(accA[4 * q + 3], accB[4 * q + 3]));
        int px0 = h * 16 + 4 * q + 2 * hh;
        if (px0 < 25) dst[px0] = fmaxf(m0 + bias, 0.f);
        if (px0 + 1 < 25) dst[px0 + 1] = fmaxf(m1 + bias, 0.f);
    }
}

// ---------------- Kernel E: final linear (float4) ----------------
__global__ __launch_bounds__(256) void k_fc(const float* __restrict__ pool2,
    const float* __restrict__ oww, const float* __restrict__ ob,
    float* __restrict__ yhat)
{
    int cls = blockIdx.x / BATCH, b = blockIdx.x % BATCH;
    int t = threadIdx.x;
    const float4* y = (const float4*)(pool2 + (size_t)b * 20000);
    const float4* w = (const float4*)(oww + (size_t)cls * 20000);
    float acc = 0.f;
    for (int k = t; k < 5000; k += 256) {
        float4 a = y[k], ww = w[k];
        acc += a.x * ww.x + a.y * ww.y + a.z * ww.z + a.w * ww.w;
    }
    #pragma unroll
    for (int off = 32; off > 0; off >>= 1)
        acc += __shfl_xor(acc, off, 64);
    __shared__ float part[4];
    if ((t & 63) == 0) part[t >> 6] = acc;
    __syncthreads();
    if (t == 0)
        yhat[b * NCLS + cls] = part[0] + part[1] + part[2] + part[3] + ob[cls];
}

extern "C" void kernel_launch(void* const* d_in, const int* in_sizes, int n_in,
                              void* d_out, int out_size, void* d_ws, size_t ws_size,
                              hipStream_t stream)
{
    const float* x   = (const float*)d_in[0];
    const int*   pi0 = (const int*)d_in[1];
    const int*   pi1 = (const int*)d_in[2];
    const float* w1  = (const float*)d_in[3];
    const float* b1  = (const float*)d_in[4];
    const float* w2  = (const float*)d_in[5];
    const float* b2  = (const float*)d_in[6];
    const float* c1w = (const float*)d_in[7];
    const float* c1b = (const float*)d_in[8];
    const float* c2w = (const float*)d_in[9];
    const float* c2b = (const float*)d_in[10];
    const float* oww = (const float*)d_in[11];
    const float* owb = (const float*)d_in[12];
    float* out = (float*)d_out;
    float* ws = (float*)d_ws;

    float*        nf     = ws + NF_OFF;
    float*        wT1    = ws + WT1_OFF;
    unsigned int* wT2b   = (unsigned int*)(ws + WT2B_OFF);
    float*        inv    = ws + INV_OFF;
    float*        imgs_p = ws + IMGSP_OFF;
    float*        pool1p = ws + POOL1P_OFF;
    float*        pool2  = ws + POOL2_OFF;

    k_init <<<2 + NZBLK, 256, 0, stream>>>(c1w, c2w, wT1, wT2b, imgs_p);
    k_filt <<<500, 256, 0, stream>>>(x, w1, b1, w2, b2, nf, out + BATCH * NCLS);
    k_pimg <<<256, 256, 0, stream>>>(nf, pi0, pi1, imgs_p);
    k_pmax <<<64, 256, 0, stream>>>(imgs_p, inv);
    k_conv1<<<1280, 256, 0, stream>>>(imgs_p, wT1, c1b, inv, pool1p);
    k_conv2<<<800, 128, 0, stream>>>(pool1p, wT2b, c2b, pool2);
    k_fc   <<<BATCH * NCLS, 256, 0, stream>>>(pool2, oww, owb, out);
}

// Round 11
// 86.329 us; speedup vs baseline: 1.1384x; 1.1384x over previous
//
#include <hip/hip_runtime.h>
#include <hip/hip_bf16.h>

#define N_NODES 16000
#define IN_F 128
#define HID 64
#define BATCH 32
#define NPAIR 128
#define DRES 100
#define NCLS 10

// workspace layout (float offsets)
#define NF_OFF     0
#define WT1_OFF    16000                     // [2 ic][25 tap][16 oc] fp32
#define WT2B_OFF   (16000 + 800)             // [200 kp][32 oc] packed bf16 pairs (uint)
#define WB1P_OFF   (WT2B_OFF + 12800)        // [8 s][2 nt][64 lane][4] packed bf16 pairs (uint)
#define INV_OFF    (WB1P_OFF + 4096)         // [64] per-(b,c) 1/max
#define IMGSP_OFF  (INV_OFF + 64)            // [32][2][104][104] padded
#define POOL1P_OFF (IMGSP_OFF + 32*2*104*104)   // [32][16][54][56] padded
#define POOL2_OFF  (POOL1P_OFF + 32*16*54*56)   // [32][32][25][25]
#define ZERO_N4    ((32*2*104*104 + 32*16*54*56) / 4)

#define NZBLK  ((ZERO_N4 + 255) / 256)

// float2 patch element access (compile-time index under full unroll)
#define PV(P, r, c) (((c) & 1) ? P[(r)*3 + ((c)>>1)].y : P[(r)*3 + ((c)>>1)].x)

typedef short short8 __attribute__((ext_vector_type(8)));
typedef float f32x16 __attribute__((ext_vector_type(16)));

static __device__ __forceinline__ unsigned short f2b(float f) {
    __hip_bfloat16 h = __float2bfloat16(f);
    return *reinterpret_cast<unsigned short*>(&h);
}
static __device__ __forceinline__ unsigned int pk2(float a, float b) {
    return (unsigned int)f2b(a) | ((unsigned int)f2b(b) << 16);
}

// element offset of k=(ic,kh,kw) within inb[16][6][56] (tile row-base 0)
#define COFF(k) (((k)/25)*336 + (((k)%25)/5)*56 + ((k)%25)%5)

// ---------------- Kernel I: weight prep + zero buffers ----------------
// bx==0: wT1; bx==1: conv2 bf16 weights; bx==2: filt w1 bf16 fragments; rest: zero.
__global__ __launch_bounds__(256) void k_init(const float* __restrict__ c1w,
    const float* __restrict__ c2w, const float* __restrict__ w1,
    float* __restrict__ wT1, unsigned int* __restrict__ wT2b,
    unsigned int* __restrict__ wb1p, float* __restrict__ zbase)
{
    int bx = blockIdx.x, t = threadIdx.x;
    if (bx == 0) {
        for (int i = t; i < 800; i += 256) {
            int ic = i / 400, tap = (i / 16) % 25, oc = i % 16;
            wT1[i] = c1w[(oc * 2 + ic) * 25 + tap];
        }
        return;
    }
    if (bx == 1) {
        for (int i = t; i < 6400; i += 256) {
            int kp = i >> 5, oc = i & 31;
            int k0 = 2 * kp, k1 = k0 + 1;
            float f0 = c2w[(oc * 16 + k0 / 25) * 25 + k0 % 25];
            float f1 = c2w[(oc * 16 + k1 / 25) * 25 + k1 % 25];
            wT2b[i] = pk2(f0, f1);
        }
        return;
    }
    if (bx == 2) {
        // wb1p[((s*2+nt)*64+lane)*4+r] = pack(w1[k0][hid], w1[k0+1][hid]),
        // k0 = s*16 + (lane>>5)*8 + 2r, hid = nt*32 + (lane&31)
        for (int i = t; i < 4096; i += 256) {
            int r = i & 3, lane = (i >> 2) & 63, nt = (i >> 8) & 1, s = i >> 9;
            int k0 = s * 16 + (lane >> 5) * 8 + 2 * r;
            int hid = nt * 32 + (lane & 31);
            wb1p[i] = pk2(w1[k0 * HID + hid], w1[(k0 + 1) * HID + hid]);
        }
        return;
    }
    int i = (bx - 3) * 256 + t;
    if (i < ZERO_N4) ((float4*)zbase)[i] = make_float4(0.f, 0.f, 0.f, 0.f);
}

// ---------------- Kernel A: node filtration MLP via MFMA ----------------
// 500 blocks x 64 thr (1 wave = 32 nodes). A = x tile (coalesced per-lane
// float4 loads, each cacheline used fully), B = pre-packed w1 fragments.
// 8 K-steps x 2 N-tiles of v_mfma_f32_32x32x16_bf16; layer-2 folded into
// epilogue via 32-lane shfl_xor reduce.
__global__ __launch_bounds__(64) void k_filt(const float* __restrict__ x,
    const unsigned int* __restrict__ wb1p, const float* __restrict__ b1,
    const float* __restrict__ w2, const float* __restrict__ b2,
    float* __restrict__ nf, float* __restrict__ out_nf)
{
    int lane = threadIdx.x;
    int n0 = blockIdx.x * 32;
    int hh = lane >> 5, sm = lane & 31;
    const float* xr = x + (size_t)(n0 + sm) * IN_F + hh * 8;

    f32x16 acc0 = {0.f,0.f,0.f,0.f,0.f,0.f,0.f,0.f,0.f,0.f,0.f,0.f,0.f,0.f,0.f,0.f};
    f32x16 acc1 = {0.f,0.f,0.f,0.f,0.f,0.f,0.f,0.f,0.f,0.f,0.f,0.f,0.f,0.f,0.f,0.f};

    #pragma unroll
    for (int s = 0; s < 8; ++s) {
        float4 v0 = *(const float4*)(xr + s * 16);
        float4 v1 = *(const float4*)(xr + s * 16 + 4);
        union { short8 v; unsigned int u[4]; } a;
        a.u[0] = pk2(v0.x, v0.y);
        a.u[1] = pk2(v0.z, v0.w);
        a.u[2] = pk2(v1.x, v1.y);
        a.u[3] = pk2(v1.z, v1.w);
        union { short8 v; uint4 q; } b0, b1f;
        b0.q  = *(const uint4*)(wb1p + ((s * 2 + 0) * 64 + lane) * 4);
        b1f.q = *(const uint4*)(wb1p + ((s * 2 + 1) * 64 + lane) * 4);
        acc0 = __builtin_amdgcn_mfma_f32_32x32x16_bf16(a.v, b0.v, acc0, 0, 0, 0);
        acc1 = __builtin_amdgcn_mfma_f32_32x32x16_bf16(a.v, b1f.v, acc1, 0, 0, 0);
    }

    // layer 2: q[r] = relu(h)*w2 summed over hid; C layout col=lane&31,
    // row m = (r&3)+8*(r>>2)+4*hh (node within tile)
    int h0 = sm, h1 = 32 + sm;
    float b10 = b1[h0], b11 = b1[h1], w20 = w2[h0], w21 = w2[h1];
    float q[16];
    #pragma unroll
    for (int r = 0; r < 16; ++r)
        q[r] = fmaxf(acc0[r] + b10, 0.f) * w20 + fmaxf(acc1[r] + b11, 0.f) * w21;
    #pragma unroll
    for (int off = 1; off < 32; off <<= 1) {
        #pragma unroll
        for (int r = 0; r < 16; ++r)
            q[r] += __shfl_xor(q[r], off, 64);
    }
    if (sm == 0) {
        float b2v = b2[0];
        #pragma unroll
        for (int r = 0; r < 16; ++r) {
            int m = (r & 3) + 8 * (r >> 2) + 4 * hh;
            float f = 1.f / (1.f + expf(-(q[r] + b2v)));
            nf[n0 + m] = f;
            out_nf[n0 + m] = f;
        }
    }
}

// ---------------- Kernel B: persistence image partial accumulate ----------------
__global__ __launch_bounds__(256) void k_pimg(const float* __restrict__ nf,
    const int* __restrict__ pi0, const int* __restrict__ pi1,
    float* __restrict__ imgs_p)
{
    int g = blockIdx.x;
    int img = (g & 7) * 8 + ((g >> 3) & 7);
    int q = g >> 6;
    int b = img >> 1, c = img & 1;
    const int* pi = c ? pi1 : pi0;
    __shared__ float sb[32], sp[32];
    int t = threadIdx.x;
    if (t < 32) {
        int p = q * 32 + t;
        int i0 = pi[(b * NPAIR + p) * 2 + 0];
        int i1 = pi[(b * NPAIR + p) * 2 + 1];
        float f0 = nf[i0], f1 = nf[i1];
        sb[t] = f0;
        sp[t] = f1 - f0;
    }
    __syncthreads();
    if (t >= 169) return;
    int ti = t / 13, tj = t % 13;
    float ci[8], cj[8];
    #pragma unroll
    for (int r = 0; r < 8; ++r) {
        ci[r] = (float)(ti + 13 * r) * 0.01f;
        cj[r] = (float)(tj + 13 * r) * 0.01f;
    }
    float acc[8][8];
    #pragma unroll
    for (int r = 0; r < 8; ++r)
        #pragma unroll
        for (int s = 0; s < 8; ++s) acc[r][s] = 0.f;
    for (int p = 0; p < 32; ++p) {
        float bb = sb[p], pp = sp[p];
        float eb[8], ep[8];
        #pragma unroll
        for (int r = 0; r < 8; ++r) { float d = bb - ci[r]; eb[r] = __expf(-d * d); }
        #pragma unroll
        for (int s = 0; s < 8; ++s) { float d = pp - cj[s]; ep[s] = __expf(-d * d); }
        #pragma unroll
        for (int r = 0; r < 8; ++r)
            #pragma unroll
            for (int s = 0; s < 8; ++s)
                acc[r][s] = fmaf(eb[r], ep[s], acc[r][s]);
    }
    float* dst = imgs_p + (size_t)img * 10816 + 2 * 104 + 2;
    #pragma unroll
    for (int r = 0; r < 8; ++r) {
        int i = ti + 13 * r;
        if (i < DRES) {
            #pragma unroll
            for (int s = 0; s < 8; ++s) {
                int j = tj + 13 * s;
                if (j < DRES) atomicAdd(&dst[i * 104 + j], acc[r][s]);
            }
        }
    }
}

// ---------------- Kernel M: per-image max -> inv ----------------
__global__ __launch_bounds__(256) void k_pmax(const float* __restrict__ imgs_p,
    float* __restrict__ inv)
{
    int img = blockIdx.x;
    const float4* src = (const float4*)(imgs_p + (size_t)img * 10816);
    int t = threadIdx.x;
    float m = 0.f;
    for (int k = t; k < 2704; k += 256) {
        float4 v = src[k];
        m = fmaxf(m, fmaxf(fmaxf(v.x, v.y), fmaxf(v.z, v.w)));
    }
    #pragma unroll
    for (int off = 32; off > 0; off >>= 1)
        m = fmaxf(m, __shfl_xor(m, off, 64));
    __shared__ float wm[4];
    if ((t & 63) == 0) wm[t >> 6] = m;
    __syncthreads();
    if (t == 0) {
        float bm = fmaxf(fmaxf(wm[0], wm[1]), fmaxf(wm[2], wm[3]));
        inv[img] = 1.f / bm;
    }
}

// ---------------- Kernel C: conv1 + relu + maxpool2 (VALU) ----------------
__global__ __launch_bounds__(256) void k_conv1(const float* __restrict__ imgs_p,
    const float* __restrict__ wT1, const float* __restrict__ cb,
    const float* __restrict__ inv, float* __restrict__ pool1p)
{
    int g = blockIdx.x;
    int b = (g & 7) * 4 + ((g >> 3) & 3);
    int ocg = (g >> 5) & 3;
    int rg = g >> 7;
    int t = threadIdx.x;
    if (t >= 250) return;
    int ow = t % 50, oh = rg * 5 + t / 50;

    float2 PA[18], PB[18];
    {
        const float* bs = imgs_p + (size_t)(b * 2 + 0) * 10816 + (2 * oh) * 104 + 2 * ow;
        #pragma unroll
        for (int r = 0; r < 6; ++r) {
            const float* rp = bs + r * 104;
            PA[r * 3 + 0] = *(const float2*)rp;
            PA[r * 3 + 1] = *(const float2*)(rp + 2);
            PA[r * 3 + 2] = *(const float2*)(rp + 4);
        }
        const float* bs1 = bs + 10816;
        #pragma unroll
        for (int r = 0; r < 6; ++r) {
            const float* rp = bs1 + r * 104;
            PB[r * 3 + 0] = *(const float2*)rp;
            PB[r * 3 + 1] = *(const float2*)(rp + 2);
            PB[r * 3 + 2] = *(const float2*)(rp + 4);
        }
    }
    float acc0[4][2][2] = {}, acc1[4][2][2] = {};
    const float* w0 = wT1 + ocg * 4;
    const float* w1r = wT1 + 400 + ocg * 4;
    #pragma unroll
    for (int kh = 0; kh < 5; ++kh)
        #pragma unroll
        for (int kw = 0; kw < 5; ++kw) {
            float4 wa = *(const float4*)(w0 + (kh * 5 + kw) * 16);
            float4 wb = *(const float4*)(w1r + (kh * 5 + kw) * 16);
            #pragma unroll
            for (int j = 0; j < 2; ++j)
                #pragma unroll
                for (int i = 0; i < 2; ++i) {
                    float va = PV(PA, kh + j, kw + i);
                    float vb = PV(PB, kh + j, kw + i);
                    acc0[0][j][i] = fmaf(va, wa.x, acc0[0][j][i]);
                    acc0[1][j][i] = fmaf(va, wa.y, acc0[1][j][i]);
                    acc0[2][j][i] = fmaf(va, wa.z, acc0[2][j][i]);
                    acc0[3][j][i] = fmaf(va, wa.w, acc0[3][j][i]);
                    acc1[0][j][i] = fmaf(vb, wb.x, acc1[0][j][i]);
                    acc1[1][j][i] = fmaf(vb, wb.y, acc1[1][j][i]);
                    acc1[2][j][i] = fmaf(vb, wb.z, acc1[2][j][i]);
                    acc1[3][j][i] = fmaf(vb, wb.w, acc1[3][j][i]);
                }
        }
    float sc0 = inv[b * 2 + 0], sc1 = inv[b * 2 + 1];
    float4 bias4 = *(const float4*)(cb + ocg * 4);
    float bv[4] = {bias4.x, bias4.y, bias4.z, bias4.w};
    #pragma unroll
    for (int o = 0; o < 4; ++o) {
        float v00 = fmaf(sc1, acc1[o][0][0], sc0 * acc0[o][0][0]);
        float v01 = fmaf(sc1, acc1[o][0][1], sc0 * acc0[o][0][1]);
        float v10 = fmaf(sc1, acc1[o][1][0], sc0 * acc0[o][1][0]);
        float v11 = fmaf(sc1, acc1[o][1][1], sc0 * acc0[o][1][1]);
        float m = fmaxf(fmaxf(v00, v01), fmaxf(v10, v11));
        pool1p[((size_t)(b * 16 + ocg * 4 + o) * 54 + oh + 2) * 56 + ow + 2] =
            fmaxf(m + bv[o], 0.f);
    }
}

// ---------------- Kernel D: conv2 via MFMA implicit GEMM ----------------
__global__ __launch_bounds__(128) void k_conv2(const float* __restrict__ pool1p,
    const unsigned int* __restrict__ wg, const float* __restrict__ cb2,
    float* __restrict__ pool2)
{
    int g = blockIdx.x;
    int b = (g & 7) * 4 + ((g >> 3) & 3);
    int py = g >> 5;
    int t = threadIdx.x;

    __shared__ unsigned short inb[5376];  // [16 ic][6 rows][56 cols] bf16
    {
        const float* src = pool1p + (size_t)b * 48384 + (2 * py) * 56;
        unsigned int* inb32 = (unsigned int*)inb;
        for (int i = t; i < 1344; i += 128) {
            int ic = i / 84, rem = i % 84;
            int r = rem / 14, c4 = rem % 14;
            float4 v = *(const float4*)(src + ic * 3024 + r * 56 + c4 * 4);
            inb32[i * 2 + 0] = pk2(v.x, v.y);
            inb32[i * 2 + 1] = pk2(v.z, v.w);
        }
    }
    __syncthreads();

    int lane = t & 63;
    int h = t >> 6;
    int hh = lane >> 5;
    int sm = lane & 31;
    int cb = h * 32 + sm; if (cb > 49) cb = 49;
    int cbA = cb, cbB = cb + 56;
    int oc = sm;
    int wbase = hh * 128 + oc;

    f32x16 accA = {0.f,0.f,0.f,0.f,0.f,0.f,0.f,0.f,0.f,0.f,0.f,0.f,0.f,0.f,0.f,0.f};
    f32x16 accB = {0.f,0.f,0.f,0.f,0.f,0.f,0.f,0.f,0.f,0.f,0.f,0.f,0.f,0.f,0.f,0.f};

    #pragma unroll
    for (int s = 0; s < 25; ++s) {
        union { short8 v; unsigned int u[4]; } bw;
        bw.u[0] = wg[wbase + s * 256 + 0];
        bw.u[1] = wg[wbase + s * 256 + 32];
        bw.u[2] = wg[wbase + s * 256 + 64];
        bw.u[3] = wg[wbase + s * 256 + 96];
        unsigned short ua[8], ub[8];
        #pragma unroll
        for (int e = 0; e < 8; ++e) {
            int o = hh ? COFF(16 * s + 8 + e) : COFF(16 * s + e);
            ua[e] = inb[cbA + o];
            ub[e] = inb[cbB + o];
        }
        union { short8 v; unsigned int u[4]; } aA, aB;
        #pragma unroll
        for (int r = 0; r < 4; ++r) {
            aA.u[r] = (unsigned int)ua[2 * r] | ((unsigned int)ua[2 * r + 1] << 16);
            aB.u[r] = (unsigned int)ub[2 * r] | ((unsigned int)ub[2 * r + 1] << 16);
        }
        accA = __builtin_amdgcn_mfma_f32_32x32x16_bf16(aA.v, bw.v, accA, 0, 0, 0);
        accB = __builtin_amdgcn_mfma_f32_32x32x16_bf16(aB.v, bw.v, accB, 0, 0, 0);
    }

    float bias = cb2[oc];
    float* dst = pool2 + ((size_t)(b * 32 + oc) * 25 + py) * 25;
    #pragma unroll
    for (int q = 0; q < 4; ++q) {
        float m0 = fmaxf(fmaxf(accA[4 * q + 0], accB[4 * q + 0]),
                         fmaxf(accA[4 * q + 1], accB[4 * q + 1]));
        float m1 = fmaxf(fmaxf(accA[4 * q + 2], accB[4 * q + 2]),
                         fmaxf(accA[4 * q + 3], accB[4 * q + 3]));
        int px0 = h * 16 + 4 * q + 2 * hh;
        if (px0 < 25) dst[px0] = fmaxf(m0 + bias, 0.f);
        if (px0 + 1 < 25) dst[px0 + 1] = fmaxf(m1 + bias, 0.f);
    }
}

// ---------------- Kernel E: final linear (float4) ----------------
__global__ __launch_bounds__(256) void k_fc(const float* __restrict__ pool2,
    const float* __restrict__ oww, const float* __restrict__ ob,
    float* __restrict__ yhat)
{
    int cls = blockIdx.x / BATCH, b = blockIdx.x % BATCH;
    int t = threadIdx.x;
    const float4* y = (const float4*)(pool2 + (size_t)b * 20000);
    const float4* w = (const float4*)(oww + (size_t)cls * 20000);
    float acc = 0.f;
    for (int k = t; k < 5000; k += 256) {
        float4 a = y[k], ww = w[k];
        acc += a.x * ww.x + a.y * ww.y + a.z * ww.z + a.w * ww.w;
    }
    #pragma unroll
    for (int off = 32; off > 0; off >>= 1)
        acc += __shfl_xor(acc, off, 64);
    __shared__ float part[4];
    if ((t & 63) == 0) part[t >> 6] = acc;
    __syncthreads();
    if (t == 0)
        yhat[b * NCLS + cls] = part[0] + part[1] + part[2] + part[3] + ob[cls];
}

extern "C" void kernel_launch(void* const* d_in, const int* in_sizes, int n_in,
                              void* d_out, int out_size, void* d_ws, size_t ws_size,
                              hipStream_t stream)
{
    const float* x   = (const float*)d_in[0];
    const int*   pi0 = (const int*)d_in[1];
    const int*   pi1 = (const int*)d_in[2];
    const float* w1  = (const float*)d_in[3];
    const float* b1  = (const float*)d_in[4];
    const float* w2  = (const float*)d_in[5];
    const float* b2  = (const float*)d_in[6];
    const float* c1w = (const float*)d_in[7];
    const float* c1b = (const float*)d_in[8];
    const float* c2w = (const float*)d_in[9];
    const float* c2b = (const float*)d_in[10];
    const float* oww = (const float*)d_in[11];
    const float* owb = (const float*)d_in[12];
    float* out = (float*)d_out;
    float* ws = (float*)d_ws;

    float*        nf     = ws + NF_OFF;
    float*        wT1    = ws + WT1_OFF;
    unsigned int* wT2b   = (unsigned int*)(ws + WT2B_OFF);
    unsigned int* wb1p   = (unsigned int*)(ws + WB1P_OFF);
    float*        inv    = ws + INV_OFF;
    float*        imgs_p = ws + IMGSP_OFF;
    float*        pool1p = ws + POOL1P_OFF;
    float*        pool2  = ws + POOL2_OFF;

    k_init <<<3 + NZBLK, 256, 0, stream>>>(c1w, c2w, w1, wT1, wT2b, wb1p, imgs_p);
    k_filt <<<500, 64, 0, stream>>>(x, wb1p, b1, w2, b2, nf, out + BATCH * NCLS);
    k_pimg <<<256, 256, 0, stream>>>(nf, pi0, pi1, imgs_p);
    k_pmax <<<64, 256, 0, stream>>>(imgs_p, inv);
    k_conv1<<<1280, 256, 0, stream>>>(imgs_p, wT1, c1b, inv, pool1p);
    k_conv2<<<800, 128, 0, stream>>>(pool1p, wT2b, c2b, pool2);
    k_fc   <<<BATCH * NCLS, 256, 0, stream>>>(pool2, oww, owb, out);
}